// Round 1
// baseline (133.424 us; speedup 1.0000x reference)
//
#include <hip/hip_runtime.h>
#include <stdint.h>

// Problem constants (fixed by the reference)
#define BATCH 2
#define SEQ 2048
#define DM 512
#define NH 8
#define DH 64
#define MROWS (BATCH * SEQ)   // 4096
#define NCHUNK 16
#define CHUNK (SEQ / NCHUNK)  // 128

typedef __attribute__((ext_vector_type(8))) short bf16x8;
typedef __attribute__((ext_vector_type(4))) float f32x4;

__device__ __forceinline__ unsigned short f2bf(float f) {
    union { float f; uint32_t u; } x; x.f = f;
    uint32_t r = x.u + 0x7fffu + ((x.u >> 16) & 1u);  // RNE
    return (unsigned short)(r >> 16);
}

// ---- fp32 -> bf16 converts -------------------------------------------------
__global__ void cvt_x(const float4* __restrict__ src, ushort4* __restrict__ dst, int n4) {
    int i = blockIdx.x * blockDim.x + threadIdx.x;
    if (i >= n4) return;
    float4 v = src[i];
    ushort4 o; o.x = f2bf(v.x); o.y = f2bf(v.y); o.z = f2bf(v.z); o.w = f2bf(v.w);
    dst[i] = o;
}

// 4 weight tensors (each 8*64*512 = 262144 elems) -> one contiguous bf16 block
__global__ void cvt_w(const float* __restrict__ w0, const float* __restrict__ w1,
                      const float* __restrict__ w2, const float* __restrict__ w3,
                      unsigned short* __restrict__ dst) {
    int i4 = (blockIdx.x * blockDim.x + threadIdx.x) * 4;   // over 1048576 elems
    const float* src = (i4 < 262144) ? w0 : (i4 < 524288) ? w1 : (i4 < 786432) ? w2 : w3;
    int off = i4 & 262143;
    float4 v = *(const float4*)(src + off);
    ushort4 o; o.x = f2bf(v.x); o.y = f2bf(v.y); o.z = f2bf(v.z); o.w = f2bf(v.w);
    *(ushort4*)(dst + i4) = o;
}

// ---- C[M,N] = A[M,K] * B[N,K]^T  (bf16 in, fp32 out), 128x128 tile, BK=32 --
// z-batched: B += z*sBz, C += z*sCz.
__global__ __launch_bounds__(256) void gemm_bt(
    const unsigned short* __restrict__ A, const unsigned short* __restrict__ Bb,
    float* __restrict__ Cb, int M, int N, int K, int sBz, int sCz)
{
    const unsigned short* B = Bb + (size_t)blockIdx.z * sBz;
    float* C = Cb + (size_t)blockIdx.z * sCz;
    __shared__ __align__(16) unsigned short As[128 * 32];
    __shared__ __align__(16) unsigned short Bs[128 * 32];
    const int t = threadIdx.x;
    const int lane = t & 63, wave = t >> 6;
    const int wm = (wave >> 1) * 64, wn = (wave & 1) * 64;
    const int m0 = blockIdx.x * 128, n0 = blockIdx.y * 128;
    const int r0 = t >> 2, s0 = (t & 3) * 8;   // staging: row, k-segment

    f32x4 acc[4][4];
#pragma unroll
    for (int i = 0; i < 4; i++)
#pragma unroll
        for (int j = 0; j < 4; j++) { f32x4 z = {0.f, 0.f, 0.f, 0.f}; acc[i][j] = z; }

    const int mrow = wm + (lane & 15);
    const int nrow = wn + (lane & 15);
    const int kcol = (lane >> 4) * 8;

    for (int k0 = 0; k0 < K; k0 += 32) {
        uint4 a0 = *(const uint4*)(A + (size_t)(m0 + r0) * K + k0 + s0);
        uint4 a1 = *(const uint4*)(A + (size_t)(m0 + r0 + 64) * K + k0 + s0);
        uint4 b0 = *(const uint4*)(B + (size_t)(n0 + r0) * K + k0 + s0);
        uint4 b1 = *(const uint4*)(B + (size_t)(n0 + r0 + 64) * K + k0 + s0);
        __syncthreads();   // previous iter's LDS reads done
        *(uint4*)(As + r0 * 32 + s0) = a0;
        *(uint4*)(As + (r0 + 64) * 32 + s0) = a1;
        *(uint4*)(Bs + r0 * 32 + s0) = b0;
        *(uint4*)(Bs + (r0 + 64) * 32 + s0) = b1;
        __syncthreads();
        bf16x8 af[4], bfr[4];
#pragma unroll
        for (int i = 0; i < 4; i++)
            af[i] = *(const bf16x8*)(As + (mrow + i * 16) * 32 + kcol);
#pragma unroll
        for (int j = 0; j < 4; j++)
            bfr[j] = *(const bf16x8*)(Bs + (nrow + j * 16) * 32 + kcol);
#pragma unroll
        for (int i = 0; i < 4; i++)
#pragma unroll
            for (int j = 0; j < 4; j++)
                acc[i][j] = __builtin_amdgcn_mfma_f32_16x16x32_bf16(af[i], bfr[j], acc[i][j], 0, 0, 0);
    }
    // C/D layout: col = lane&15, row = (lane>>4)*4 + reg  [m89/m91-verified]
    const int crow = m0 + wm + (lane >> 4) * 4;
    const int ccol = n0 + wn + (lane & 15);
#pragma unroll
    for (int i = 0; i < 4; i++)
#pragma unroll
        for (int j = 0; j < 4; j++)
#pragma unroll
            for (int r = 0; r < 4; r++)
                C[(size_t)(crow + i * 16 + r) * N + ccol + j * 16] = acc[i][j][r];
}

// ---- diagonal score -> softmax coefficients --------------------------------
// attn row q: weight a=e^{d-M}/Z on diagonal, w=e^{-M}/Z on each p>q; p<q exact 0.
__global__ void coef_k(const float* __restrict__ Q, const float* __restrict__ Kq,
                       float* __restrict__ cA, float* __restrict__ cW) {
    int idx = blockIdx.x * blockDim.x + threadIdx.x;   // 32768 = MROWS*NH
    int bp = idx >> 3, head = idx & 7;
    const float4* q = (const float4*)(Q + (size_t)bp * DM + head * DH);
    const float4* k = (const float4*)(Kq + (size_t)bp * DM + head * DH);
    float s = 0.f;
#pragma unroll
    for (int j = 0; j < 16; j++) {
        float4 a = q[j], b = k[j];
        s += a.x * b.x + a.y * b.y + a.z * b.z + a.w * b.w;
    }
    int p = bp & (SEQ - 1);
    float cnt = (float)(SEQ - 1 - p);
    float d = s * 0.125f;            // / sqrt(64)
    float M = fmaxf(d, 0.f);
    float a = expf(d - M);
    float e0 = expf(-M);
    float Z = a + cnt * e0;
    cA[idx] = a / Z;
    cW[idx] = e0 / Z;
}

// ---- suffix sums of V (chunked) --------------------------------------------
__global__ void vsuffix(const float* __restrict__ V, float* __restrict__ csum) {
    int blk = blockIdx.x;                 // (b*NH + i)*NCHUNK + c
    int c = blk % NCHUNK, bi = blk / NCHUNK;
    int i = bi % NH, b = bi / NH;
    int h = threadIdx.x;
    const float* v = V + (size_t)(b * SEQ + c * CHUNK) * DM + i * DH + h;
    float s = 0.f;
    for (int j = 0; j < CHUNK; j++) s += v[(size_t)j * DM];
    csum[blk * 64 + h] = s;
}

// z[q] = a*v[q] + w * sum_{p>q} v[p];  write bf16 Z matrix [MROWS, 512]
__global__ void zbuild(const float* __restrict__ V, const float* __restrict__ csum,
                       const float* __restrict__ cA, const float* __restrict__ cW,
                       unsigned short* __restrict__ Zb) {
    int blk = blockIdx.x;
    int c = blk % NCHUNK, bi = blk / NCHUNK;
    int i = bi % NH, b = bi / NH;
    int h = threadIdx.x;
    float r = 0.f;
    for (int cc = c + 1; cc < NCHUNK; cc++) r += csum[(bi * NCHUNK + cc) * 64 + h];
    for (int j = CHUNK - 1; j >= 0; j--) {
        int p = c * CHUNK + j;
        size_t row = (size_t)(b * SEQ + p);
        float v = V[row * DM + i * DH + h];
        float a = cA[row * NH + i], w = cW[row * NH + i];
        Zb[row * DM + i * DH + h] = f2bf(a * v + w * r);
        r += v;
    }
}

extern "C" void kernel_launch(void* const* d_in, const int* in_sizes, int n_in,
                              void* d_out, int out_size, void* d_ws, size_t ws_size,
                              hipStream_t stream) {
    const float* x  = (const float*)d_in[0];
    const float* Wq = (const float*)d_in[1];
    const float* Wk = (const float*)d_in[2];
    const float* Wv = (const float*)d_in[3];
    const float* Wo = (const float*)d_in[4];
    float* out = (float*)d_out;     // [2,2048,512] fp32
    char* ws = (char*)d_ws;         // needs ~36 MB

    unsigned short* xb = (unsigned short*)(ws);             // 4 MB   [4096,512] bf16
    unsigned short* wb = (unsigned short*)(ws + 4194304);   // 2 MB   Wq|Wk|Wv|Wo bf16
    float* Q  = (float*)(ws + 6291456);                     // 8 MB   [4096,512]
    float* Kp = (float*)(ws + 14680064);                    // 8 MB
    float* V  = (float*)(ws + 23068672);                    // 8 MB
    float* cA = (float*)(ws + 31457280);                    // 128 KB [4096,8]
    float* cW = (float*)(ws + 31588352);                    // 128 KB
    float* cs = (float*)(ws + 31719424);                    // 64 KB  [2*8*16,64]
    unsigned short* Zb = (unsigned short*)(ws + 31784960);  // 4 MB   [4096,512] bf16

    cvt_x<<<2048, 256, 0, stream>>>((const float4*)x, (ushort4*)xb, 524288);
    cvt_w<<<1024, 256, 0, stream>>>(Wq, Wk, Wv, Wo, wb);
    // Q|K|V = x @ W^T, z-batched over the three weight blocks
    gemm_bt<<<dim3(32, 4, 3), 256, 0, stream>>>(xb, wb, Q, MROWS, DM, DM, 262144, 2097152);
    coef_k<<<128, 256, 0, stream>>>(Q, Kp, cA, cW);
    vsuffix<<<BATCH * NH * NCHUNK, 64, 0, stream>>>(V, cs);
    zbuild<<<BATCH * NH * NCHUNK, 64, 0, stream>>>(V, cs, cA, cW, Zb);
    // out = Z @ Wo^T
    gemm_bt<<<dim3(32, 4, 1), 256, 0, stream>>>(Zb, wb + 786432, out, MROWS, DM, DM, 0, 0);
}

// Round 2
// 125.373 us; speedup vs baseline: 1.0642x; 1.0642x over previous
//
#include <hip/hip_runtime.h>
#include <stdint.h>

// Problem constants (fixed by the reference)
#define BATCH 2
#define SEQ 2048
#define DM 512
#define NH 8
#define DH 64
#define MROWS (BATCH * SEQ)   // 4096
#define NCHUNK 64
#define CHUNK (SEQ / NCHUNK)  // 32

typedef __attribute__((ext_vector_type(8))) short bf16x8;
typedef __attribute__((ext_vector_type(4))) float f32x4;

__device__ __forceinline__ unsigned short f2bf(float f) {
    union { float f; uint32_t u; } x; x.f = f;
    uint32_t r = x.u + 0x7fffu + ((x.u >> 16) & 1u);  // RNE
    return (unsigned short)(r >> 16);
}

// async global->LDS, 16B per lane; LDS dest = wave-uniform base + lane*16
__device__ __forceinline__ void gl_lds16(const void* g, void* l) {
    __builtin_amdgcn_global_load_lds(
        (const __attribute__((address_space(1))) void*)(uintptr_t)g,
        (__attribute__((address_space(3))) void*)(uint32_t)(uintptr_t)l,
        16, 0, 0);
}

// ---- fp32 -> bf16 converts: x and the 4 weight tensors, one kernel --------
// x: 524288 quads; each weight: 65536 quads; total 786432 quads.
__global__ void cvt_all(const float4* __restrict__ x,
                        const float* __restrict__ w0, const float* __restrict__ w1,
                        const float* __restrict__ w2, const float* __restrict__ w3,
                        ushort4* __restrict__ xb, ushort4* __restrict__ wb) {
    int i = blockIdx.x * blockDim.x + threadIdx.x;
    float4 v; ushort4* dst; int off;
    if (i < 524288) {
        v = x[i]; dst = xb; off = i;
    } else {
        int j = i - 524288;
        int wsel = j >> 16, wo = j & 65535;
        const float4* src = (const float4*)(wsel == 0 ? w0 : wsel == 1 ? w1 : wsel == 2 ? w2 : w3);
        v = src[wo]; dst = wb; off = j;
    }
    ushort4 o; o.x = f2bf(v.x); o.y = f2bf(v.y); o.z = f2bf(v.z); o.w = f2bf(v.w);
    dst[off] = o;
}

// ---- C[M,N] = A[M,K] * B[N,K]^T  (bf16 in, fp32 out), 128x128 tile, BK=32 --
// m97 structure: global_load_lds width=16 staging. z-batched: B += z*sBz, C += z*sCz.
__global__ __launch_bounds__(256) void gemm_bt(
    const unsigned short* __restrict__ A, const unsigned short* __restrict__ Bb,
    float* __restrict__ Cb, int M, int N, int K, int sBz, int sCz)
{
    const unsigned short* B = Bb + (size_t)blockIdx.z * sBz;
    float* C = Cb + (size_t)blockIdx.z * sCz;
    __shared__ __align__(16) unsigned short As[128 * 32];
    __shared__ __align__(16) unsigned short Bs[128 * 32];
    const int t = threadIdx.x;
    const int lane = t & 63, wave = t >> 6;
    const int wm = (wave >> 1) * 64, wn = (wave & 1) * 64;
    const int m0 = blockIdx.x * 128, n0 = blockIdx.y * 128;
    // staging: chunk = 16 rows (1 KB); wave w stages chunks {w, w+4} of As and Bs.
    const int lr = lane >> 2;          // row within chunk
    const int lc = (lane & 3) * 8;     // ushort col within row

    f32x4 acc[4][4];
#pragma unroll
    for (int i = 0; i < 4; i++)
#pragma unroll
        for (int j = 0; j < 4; j++) { f32x4 z = {0.f, 0.f, 0.f, 0.f}; acc[i][j] = z; }

    const int mrow = wm + (lane & 15);
    const int nrow = wn + (lane & 15);
    const int kcol = (lane >> 4) * 8;

    for (int k0 = 0; k0 < K; k0 += 32) {
        __syncthreads();   // previous iter's LDS reads done before overwrite
        gl_lds16(A + (size_t)(m0 + wave * 16 + lr) * K + k0 + lc,      As + wave * 512);
        gl_lds16(A + (size_t)(m0 + 64 + wave * 16 + lr) * K + k0 + lc, As + 2048 + wave * 512);
        gl_lds16(B + (size_t)(n0 + wave * 16 + lr) * K + k0 + lc,      Bs + wave * 512);
        gl_lds16(B + (size_t)(n0 + 64 + wave * 16 + lr) * K + k0 + lc, Bs + 2048 + wave * 512);
        __syncthreads();   // drains vmcnt (global_load_lds) per barrier semantics
        bf16x8 af[4], bfr[4];
#pragma unroll
        for (int i = 0; i < 4; i++)
            af[i] = *(const bf16x8*)(As + (mrow + i * 16) * 32 + kcol);
#pragma unroll
        for (int j = 0; j < 4; j++)
            bfr[j] = *(const bf16x8*)(Bs + (nrow + j * 16) * 32 + kcol);
#pragma unroll
        for (int i = 0; i < 4; i++)
#pragma unroll
            for (int j = 0; j < 4; j++)
                acc[i][j] = __builtin_amdgcn_mfma_f32_16x16x32_bf16(af[i], bfr[j], acc[i][j], 0, 0, 0);
    }
    // C/D layout: col = lane&15, row = (lane>>4)*4 + reg  [m89/m91-verified]
    const int crow = m0 + wm + (lane >> 4) * 4;
    const int ccol = n0 + wn + (lane & 15);
#pragma unroll
    for (int i = 0; i < 4; i++)
#pragma unroll
        for (int j = 0; j < 4; j++)
#pragma unroll
            for (int r = 0; r < 4; r++)
                C[(size_t)(crow + i * 16 + r) * N + ccol + j * 16] = acc[i][j][r];
}

// ---- fused: diagonal softmax coefficients + chunked V partial sums ---------
// blocks 0..127: coef (idx = blk*256+t over MROWS*NH)
// blocks 128..383: vsuffix; each block does 4 chunks (sub-wave per chunk)
__global__ __launch_bounds__(256) void coef_vsuf(
    const float* __restrict__ Q, const float* __restrict__ Kq,
    const float* __restrict__ V, float* __restrict__ cA, float* __restrict__ cW,
    float* __restrict__ csum) {
    int blk = blockIdx.x;
    if (blk < 128) {
        int idx = blk * 256 + threadIdx.x;   // 32768 = MROWS*NH
        int bp = idx >> 3, head = idx & 7;
        const float4* q = (const float4*)(Q + (size_t)bp * DM + head * DH);
        const float4* k = (const float4*)(Kq + (size_t)bp * DM + head * DH);
        float s = 0.f;
#pragma unroll
        for (int j = 0; j < 16; j++) {
            float4 a = q[j], b = k[j];
            s += a.x * b.x + a.y * b.y + a.z * b.z + a.w * b.w;
        }
        int p = bp & (SEQ - 1);
        float cnt = (float)(SEQ - 1 - p);
        float d = s * 0.125f;            // / sqrt(64)
        float M = fmaxf(d, 0.f);
        float a = expf(d - M);
        float e0 = expf(-M);
        float Z = a + cnt * e0;
        cA[idx] = a / Z;
        cW[idx] = e0 / Z;
    } else {
        int ci = (blk - 128) * 4 + (threadIdx.x >> 6);  // chunk id: (bi*NCHUNK + c)
        int h = threadIdx.x & 63;
        int c = ci & (NCHUNK - 1), bi = ci >> 6;
        int i = bi & 7, b = bi >> 3;
        const float* v = V + (size_t)(b * SEQ + c * CHUNK) * DM + i * DH + h;
        float s = 0.f;
#pragma unroll
        for (int j = 0; j < CHUNK; j++) s += v[(size_t)j * DM];
        csum[ci * 64 + h] = s;
    }
}

// z[q] = a*v[q] + w * sum_{p>q} v[p];  write bf16 Z matrix [MROWS, 512]
// 256 blocks x 256 threads; each sub-wave handles one chunk (serial len 32)
__global__ __launch_bounds__(256) void zbuild(
    const float* __restrict__ V, const float* __restrict__ csum,
    const float* __restrict__ cA, const float* __restrict__ cW,
    unsigned short* __restrict__ Zb) {
    int ci = blockIdx.x * 4 + (threadIdx.x >> 6);
    int h = threadIdx.x & 63;
    int c = ci & (NCHUNK - 1), bi = ci >> 6;
    int i = bi & 7, b = bi >> 3;
    float r = 0.f;
    for (int cc = c + 1; cc < NCHUNK; cc++) r += csum[((bi << 6) + cc) * 64 + h];
    for (int j = CHUNK - 1; j >= 0; j--) {
        int p = c * CHUNK + j;
        size_t row = (size_t)(b * SEQ + p);
        float v = V[row * DM + i * DH + h];
        float a = cA[row * NH + i], w = cW[row * NH + i];
        Zb[row * DM + i * DH + h] = f2bf(fmaf(a, v, w * r));
        r += v;
    }
}

extern "C" void kernel_launch(void* const* d_in, const int* in_sizes, int n_in,
                              void* d_out, int out_size, void* d_ws, size_t ws_size,
                              hipStream_t stream) {
    const float* x  = (const float*)d_in[0];
    const float* Wq = (const float*)d_in[1];
    const float* Wk = (const float*)d_in[2];
    const float* Wv = (const float*)d_in[3];
    const float* Wo = (const float*)d_in[4];
    float* out = (float*)d_out;     // [2,2048,512] fp32
    char* ws = (char*)d_ws;         // ~35 MB used

    unsigned short* xb = (unsigned short*)(ws);             // 4 MB   [4096,512] bf16
    unsigned short* wb = (unsigned short*)(ws + 4194304);   // 2 MB   Wq|Wk|Wv|Wo bf16
    float* Q  = (float*)(ws + 6291456);                     // 8 MB   [4096,512]
    float* Kp = (float*)(ws + 14680064);                    // 8 MB
    float* V  = (float*)(ws + 23068672);                    // 8 MB
    float* cA = (float*)(ws + 31457280);                    // 128 KB [4096,8]
    float* cW = (float*)(ws + 31588352);                    // 128 KB
    float* cs = (float*)(ws + 31719424);                    // 256 KB [2*8*64,64]
    unsigned short* Zb = (unsigned short*)(ws + 31981568);  // 4 MB   [4096,512] bf16

    cvt_all<<<3072, 256, 0, stream>>>((const float4*)x, Wq, Wk, Wv, Wo,
                                      (ushort4*)xb, (ushort4*)wb);
    // Q|K|V = x @ W^T, z-batched over the three weight blocks
    gemm_bt<<<dim3(32, 4, 3), 256, 0, stream>>>(xb, wb, Q, MROWS, DM, DM, 262144, 2097152);
    coef_vsuf<<<384, 256, 0, stream>>>(Q, Kp, V, cA, cW, cs);
    zbuild<<<256, 256, 0, stream>>>(V, cs, cA, cW, Zb);
    // out = Z @ Wo^T
    gemm_bt<<<dim3(32, 4, 1), 256, 0, stream>>>(Zb, wb + 786432, out, MROWS, DM, DM, 0, 0);
}

// Round 3
// 116.613 us; speedup vs baseline: 1.1442x; 1.0751x over previous
//
#include <hip/hip_runtime.h>
#include <stdint.h>

// Problem constants (fixed by the reference)
#define BATCH 2
#define SEQ 2048
#define DM 512
#define NH 8
#define DH 64
#define MROWS (BATCH * SEQ)   // 4096
#define NCHUNK 64
#define CHUNK (SEQ / NCHUNK)  // 32

typedef __attribute__((ext_vector_type(8))) short bf16x8;
typedef __attribute__((ext_vector_type(4))) float f32x4;

__device__ __forceinline__ unsigned short f2bf(float f) {
    union { float f; uint32_t u; } x; x.f = f;
    uint32_t r = x.u + 0x7fffu + ((x.u >> 16) & 1u);  // RNE
    return (unsigned short)(r >> 16);
}

// async global->LDS, 16B per lane; LDS dest = wave-uniform base + lane*16
__device__ __forceinline__ void gl_lds16(const void* g, void* l) {
    __builtin_amdgcn_global_load_lds(
        (const __attribute__((address_space(1))) void*)(uintptr_t)g,
        (__attribute__((address_space(3))) void*)(uint32_t)(uintptr_t)l,
        16, 0, 0);
}

// ---- fp32 -> bf16 converts: x and the 4 weight tensors, one kernel --------
__global__ void cvt_all(const float4* __restrict__ x,
                        const float* __restrict__ w0, const float* __restrict__ w1,
                        const float* __restrict__ w2, const float* __restrict__ w3,
                        ushort4* __restrict__ xb, ushort4* __restrict__ wb) {
    int i = blockIdx.x * blockDim.x + threadIdx.x;
    float4 v; ushort4* dst; int off;
    if (i < 524288) {
        v = x[i]; dst = xb; off = i;
    } else {
        int j = i - 524288;
        int wsel = j >> 16, wo = j & 65535;
        const float4* src = (const float4*)(wsel == 0 ? w0 : wsel == 1 ? w1 : wsel == 2 ? w2 : w3);
        v = src[wo]; dst = wb; off = j;
    }
    ushort4 o; o.x = f2bf(v.x); o.y = f2bf(v.y); o.z = f2bf(v.z); o.w = f2bf(v.w);
    dst[off] = o;
}

// ---- C[M,N] = A[M,K] * B[N,K]^T (bf16 in, fp32 out) ------------------------
// Templated tile: TM x TN block tile, WM x WN per-wave tile, BK=32, 256 thr.
// Unified LDS staging region: A rows [0,TM) then B rows [TM,TM+TN), 64B/row.
// z-batched: B += z*sBz, C += z*sCz.
template<int TM, int TN, int WM, int WN>
__global__ __launch_bounds__(256) void gemm_bt(
    const unsigned short* __restrict__ A, const unsigned short* __restrict__ Bb,
    float* __restrict__ Cb, int M, int N, int K, int sBz, int sCz)
{
    constexpr int ROWS = TM + TN;          // staged rows per K-step
    constexpr int ROUNDS = ROWS / 64;      // glds rounds (4 waves x 16 rows)
    constexpr int MI = WM / 16, NJ = WN / 16;
    constexpr int WAVES_N = TN / WN;
    const unsigned short* B = Bb + (size_t)blockIdx.z * sBz;
    float* C = Cb + (size_t)blockIdx.z * sCz;
    __shared__ __align__(16) unsigned short S[ROWS * 32];
    const int t = threadIdx.x, lane = t & 63, wave = t >> 6;
    const int wm = (wave / WAVES_N) * WM, wn = (wave % WAVES_N) * WN;
    const int m0 = blockIdx.x * TM, n0 = blockIdx.y * TN;
    const int lr = lane >> 2, lc = (lane & 3) * 8;

    // per-round global base pointers (k0-independent); wave-uniform A/B choice
    const unsigned short* gbase[ROUNDS];
#pragma unroll
    for (int r = 0; r < ROUNDS; r++) {
        int grow = r * 64 + wave * 16 + lr;
        gbase[r] = (grow < TM) ? A + (size_t)(m0 + grow) * K + lc
                               : B + (size_t)(n0 + grow - TM) * K + lc;
    }

    f32x4 acc[MI][NJ];
#pragma unroll
    for (int i = 0; i < MI; i++)
#pragma unroll
        for (int j = 0; j < NJ; j++) { f32x4 z = {0.f, 0.f, 0.f, 0.f}; acc[i][j] = z; }

    const int mrow = wm + (lane & 15);
    const int nrow = TM + wn + (lane & 15);
    const int kcol = (lane >> 4) * 8;

    for (int k0 = 0; k0 < K; k0 += 32) {
        __syncthreads();   // previous iter's LDS reads done before overwrite
#pragma unroll
        for (int r = 0; r < ROUNDS; r++)
            gl_lds16(gbase[r] + k0, S + (r * 64 + wave * 16) * 32);
        __syncthreads();   // drains vmcnt (global_load_lds) per barrier semantics
        bf16x8 af[MI], bfr[NJ];
#pragma unroll
        for (int i = 0; i < MI; i++)
            af[i] = *(const bf16x8*)(S + (mrow + i * 16) * 32 + kcol);
#pragma unroll
        for (int j = 0; j < NJ; j++)
            bfr[j] = *(const bf16x8*)(S + (nrow + j * 16) * 32 + kcol);
#pragma unroll
        for (int i = 0; i < MI; i++)
#pragma unroll
            for (int j = 0; j < NJ; j++)
                acc[i][j] = __builtin_amdgcn_mfma_f32_16x16x32_bf16(af[i], bfr[j], acc[i][j], 0, 0, 0);
    }
    // C/D layout: col = lane&15, row = (lane>>4)*4 + reg  [m89/m91-verified]
    const int crow = m0 + wm + (lane >> 4) * 4;
    const int ccol = n0 + wn + (lane & 15);
#pragma unroll
    for (int i = 0; i < MI; i++)
#pragma unroll
        for (int j = 0; j < NJ; j++)
#pragma unroll
            for (int r = 0; r < 4; r++)
                C[(size_t)(crow + i * 16 + r) * N + ccol + j * 16] = acc[i][j][r];
}

// ---- fused: diagonal softmax coefficients + chunked V partial sums ---------
// blocks 0..127: coef (idx = blk*256+t over MROWS*NH)
// blocks 128..383: vsuffix; each block does 4 chunks (sub-wave per chunk)
__global__ __launch_bounds__(256) void coef_vsuf(
    const float* __restrict__ Q, const float* __restrict__ Kq,
    const float* __restrict__ V, float* __restrict__ cA, float* __restrict__ cW,
    float* __restrict__ csum) {
    int blk = blockIdx.x;
    if (blk < 128) {
        int idx = blk * 256 + threadIdx.x;   // 32768 = MROWS*NH
        int bp = idx >> 3, head = idx & 7;
        const float4* q = (const float4*)(Q + (size_t)bp * DM + head * DH);
        const float4* k = (const float4*)(Kq + (size_t)bp * DM + head * DH);
        float s = 0.f;
#pragma unroll
        for (int j = 0; j < 16; j++) {
            float4 a = q[j], b = k[j];
            s += a.x * b.x + a.y * b.y + a.z * b.z + a.w * b.w;
        }
        int p = bp & (SEQ - 1);
        float cnt = (float)(SEQ - 1 - p);
        float d = s * 0.125f;            // / sqrt(64)
        float M = fmaxf(d, 0.f);
        float a = expf(d - M);
        float e0 = expf(-M);
        float Z = a + cnt * e0;
        cA[idx] = a / Z;
        cW[idx] = e0 / Z;
    } else {
        int ci = (blk - 128) * 4 + (threadIdx.x >> 6);  // chunk id: (bi*NCHUNK + c)
        int h = threadIdx.x & 63;
        int c = ci & (NCHUNK - 1), bi = ci >> 6;
        int i = bi & 7, b = bi >> 3;
        const float* v = V + (size_t)(b * SEQ + c * CHUNK) * DM + i * DH + h;
        float s = 0.f;
#pragma unroll
        for (int j = 0; j < CHUNK; j++) s += v[(size_t)j * DM];
        csum[ci * 64 + h] = s;
    }
}

// z[q] = a*v[q] + w * sum_{p>q} v[p];  write bf16 Z matrix [MROWS, 512]
// 256 blocks x 256 threads; each sub-wave handles one chunk (serial len 32)
__global__ __launch_bounds__(256) void zbuild(
    const float* __restrict__ V, const float* __restrict__ csum,
    const float* __restrict__ cA, const float* __restrict__ cW,
    unsigned short* __restrict__ Zb) {
    int ci = blockIdx.x * 4 + (threadIdx.x >> 6);
    int h = threadIdx.x & 63;
    int c = ci & (NCHUNK - 1), bi = ci >> 6;
    int i = bi & 7, b = bi >> 3;
    float r = 0.f;
    for (int cc = c + 1; cc < NCHUNK; cc++) r += csum[((bi << 6) + cc) * 64 + h];
    for (int j = CHUNK - 1; j >= 0; j--) {
        int p = c * CHUNK + j;
        size_t row = (size_t)(b * SEQ + p);
        float v = V[row * DM + i * DH + h];
        float a = cA[row * NH + i], w = cW[row * NH + i];
        Zb[row * DM + i * DH + h] = f2bf(fmaf(a, v, w * r));
        r += v;
    }
}

extern "C" void kernel_launch(void* const* d_in, const int* in_sizes, int n_in,
                              void* d_out, int out_size, void* d_ws, size_t ws_size,
                              hipStream_t stream) {
    const float* x  = (const float*)d_in[0];
    const float* Wq = (const float*)d_in[1];
    const float* Wk = (const float*)d_in[2];
    const float* Wv = (const float*)d_in[3];
    const float* Wo = (const float*)d_in[4];
    float* out = (float*)d_out;     // [2,2048,512] fp32
    char* ws = (char*)d_ws;         // ~35 MB used

    unsigned short* xb = (unsigned short*)(ws);             // 4 MB   [4096,512] bf16
    unsigned short* wb = (unsigned short*)(ws + 4194304);   // 2 MB   Wq|Wk|Wv|Wo bf16
    float* Q  = (float*)(ws + 6291456);                     // 8 MB   [4096,512]
    float* Kp = (float*)(ws + 14680064);                    // 8 MB
    float* V  = (float*)(ws + 23068672);                    // 8 MB
    float* cA = (float*)(ws + 31457280);                    // 128 KB [4096,8]
    float* cW = (float*)(ws + 31588352);                    // 128 KB
    float* cs = (float*)(ws + 31719424);                    // 256 KB [2*8*64,64]
    unsigned short* Zb = (unsigned short*)(ws + 31981568);  // 4 MB   [4096,512] bf16

    cvt_all<<<3072, 256, 0, stream>>>((const float4*)x, Wq, Wk, Wv, Wo,
                                      (ushort4*)xb, (ushort4*)wb);
    // Q|K|V = x @ W^T, z-batched; 128x64 tile -> 768 blocks (3/CU)
    gemm_bt<128, 64, 32, 64><<<dim3(32, 8, 3), 256, 0, stream>>>(
        xb, wb, Q, MROWS, DM, DM, 262144, 2097152);
    coef_vsuf<<<384, 256, 0, stream>>>(Q, Kp, V, cA, cW, cs);
    zbuild<<<256, 256, 0, stream>>>(V, cs, cA, cW, Zb);
    // out = Z @ Wo^T; 64x64 tile -> 512 blocks (2/CU)
    gemm_bt<64, 64, 32, 32><<<dim3(64, 8, 1), 256, 0, stream>>>(
        Zb, wb + 786432, out, MROWS, DM, DM, 0, 0);
}

// Round 4
// 114.334 us; speedup vs baseline: 1.1670x; 1.0199x over previous
//
#include <hip/hip_runtime.h>
#include <stdint.h>

// Problem constants (fixed by the reference)
#define BATCH 2
#define SEQ 2048
#define DM 512
#define NH 8
#define DH 64
#define MROWS (BATCH * SEQ)   // 4096
#define NCHUNK 64
#define CHUNK (SEQ / NCHUNK)  // 32

typedef __attribute__((ext_vector_type(8))) short bf16x8;
typedef __attribute__((ext_vector_type(4))) float f32x4;

__device__ __forceinline__ unsigned short f2bf(float f) {
    union { float f; uint32_t u; } x; x.f = f;
    uint32_t r = x.u + 0x7fffu + ((x.u >> 16) & 1u);  // RNE
    return (unsigned short)(r >> 16);
}
__device__ __forceinline__ float bf2f(unsigned short s) {
    union { uint32_t u; float f; } x; x.u = ((uint32_t)s) << 16;
    return x.f;
}

// async global->LDS, 16B per lane; LDS dest = wave-uniform base + lane*16
__device__ __forceinline__ void gl_lds16(const void* g, void* l) {
    __builtin_amdgcn_global_load_lds(
        (const __attribute__((address_space(1))) void*)(uintptr_t)g,
        (__attribute__((address_space(3))) void*)(uint32_t)(uintptr_t)l,
        16, 0, 0);
}

// ---- fp32 -> bf16 converts: x + weights, one kernel ------------------------
// wb layout (ushort elems): wqk [0,524288): per head 128 rows (Wq_i 64 | Wk_i 64);
//                           wv  [524288,786432): Wv flat [512,512];
//                           wo  [786432,1048576): Wo flat [512,512].
__global__ void cvt_all(const float4* __restrict__ x,
                        const float4* __restrict__ Wq, const float4* __restrict__ Wk,
                        const float4* __restrict__ Wv, const float4* __restrict__ Wo,
                        ushort4* __restrict__ xb, ushort4* __restrict__ wb) {
    int i = blockIdx.x * blockDim.x + threadIdx.x;   // 786432 quads total
    float4 v; ushort4* dst; int off;
    if (i < 524288) {
        v = x[i]; dst = xb; off = i;
    } else {
        int j = i - 524288;
        if (j < 131072) {            // wqk, interleaved per head
            int head = j >> 14, rp = (j >> 7) & 127, colq = j & 127;
            v = (rp < 64) ? Wq[head * 8192 + rp * 128 + colq]
                          : Wk[head * 8192 + (rp - 64) * 128 + colq];
        } else if (j < 196608) {     // wv direct
            v = Wv[j - 131072];
        } else {                     // wo direct
            v = Wo[j - 196608];
        }
        dst = wb; off = j;
    }
    ushort4 o; o.x = f2bf(v.x); o.y = f2bf(v.y); o.z = f2bf(v.z); o.w = f2bf(v.w);
    dst[off] = o;
}

// ---- fused projection kernel ----------------------------------------------
// blocks 0..255:   QK-diag: per (m-tile, head), C=[128 x (q64|k64)];
//                  epilogue: d=diag(QK^T) -> softmax coefs cA,cW. No Q/K writes.
// blocks 256..511: V = x @ Wv^T, bf16 out; epilogue: per-32-row chunk sums -> csum.
__global__ __launch_bounds__(256) void proj(
    const unsigned short* __restrict__ xb, const unsigned short* __restrict__ wb,
    float* __restrict__ cA, float* __restrict__ cW,
    unsigned short* __restrict__ V, float* __restrict__ csum)
{
    __shared__ __align__(16) unsigned short S[256 * 32];   // 16 KB
    const int t = threadIdx.x, lane = t & 63, wave = t >> 6;
    const int lr = lane >> 2, lc = (lane & 3) * 8;
    const int bid = blockIdx.x;
    const int wm = wave * 32;
    const int kcol = (lane >> 4) * 8;
    const int l15 = lane & 15;

    if (bid < 256) {
        const int head = bid & 7, m0 = (bid >> 3) * 128;
        const unsigned short* B = wb + head * 65536;   // [128,512] q|k rows
        const unsigned short* gb[4];
#pragma unroll
        for (int r = 0; r < 4; r++) {
            int grow = r * 64 + wave * 16 + lr;
            gb[r] = (grow < 128) ? xb + (size_t)(m0 + grow) * 512 + lc
                                 : B + (size_t)(grow - 128) * 512 + lc;
        }
        f32x4 acc[2][8];
#pragma unroll
        for (int i = 0; i < 2; i++)
#pragma unroll
            for (int j = 0; j < 8; j++) { f32x4 z = {0.f,0.f,0.f,0.f}; acc[i][j] = z; }
        for (int k0 = 0; k0 < 512; k0 += 32) {
            __syncthreads();
#pragma unroll
            for (int r = 0; r < 4; r++)
                gl_lds16(gb[r] + k0, S + (r * 64 + wave * 16) * 32);
            __syncthreads();
            bf16x8 af[2], bfr[8];
#pragma unroll
            for (int i = 0; i < 2; i++)
                af[i] = *(const bf16x8*)(S + (wm + i * 16 + l15) * 32 + kcol);
#pragma unroll
            for (int j = 0; j < 8; j++)
                bfr[j] = *(const bf16x8*)(S + (128 + j * 16 + l15) * 32 + kcol);
#pragma unroll
            for (int i = 0; i < 2; i++)
#pragma unroll
                for (int j = 0; j < 8; j++)
                    acc[i][j] = __builtin_amdgcn_mfma_f32_16x16x32_bf16(af[i], bfr[j], acc[i][j], 0, 0, 0);
        }
        // epilogue: d[row] = sum_h q[h]*k[h]; q col h = tile j=h>>4, k col 64+h = tile j+4, same lane
#pragma unroll
        for (int i = 0; i < 2; i++)
#pragma unroll
            for (int r = 0; r < 4; r++) {
                float d = 0.f;
#pragma unroll
                for (int j = 0; j < 4; j++) d += acc[i][j][r] * acc[i][j + 4][r];
                d += __shfl_xor(d, 1); d += __shfl_xor(d, 2);
                d += __shfl_xor(d, 4); d += __shfl_xor(d, 8);
                if (l15 == 0) {
                    int row = m0 + wm + i * 16 + (lane >> 4) * 4 + r;
                    int p = row & (SEQ - 1);
                    float dd = d * 0.125f;
                    float M = fmaxf(dd, 0.f);
                    float a = expf(dd - M), e0 = expf(-M);
                    float Z = a + (float)(SEQ - 1 - p) * e0;
                    cA[row * NH + head] = a / Z;
                    cW[row * NH + head] = e0 / Z;
                }
            }
    } else {
        const int b2 = bid - 256;
        const int head = b2 & 7, m0 = (b2 >> 3) * 128, n0 = head * 64;
        const unsigned short* B = wb + 524288 + (size_t)n0 * 512;
        const unsigned short* gb[3];
#pragma unroll
        for (int r = 0; r < 3; r++) {
            int grow = r * 64 + wave * 16 + lr;
            gb[r] = (grow < 128) ? xb + (size_t)(m0 + grow) * 512 + lc
                                 : B + (size_t)(grow - 128) * 512 + lc;
        }
        f32x4 acc[2][4];
#pragma unroll
        for (int i = 0; i < 2; i++)
#pragma unroll
            for (int j = 0; j < 4; j++) { f32x4 z = {0.f,0.f,0.f,0.f}; acc[i][j] = z; }
        for (int k0 = 0; k0 < 512; k0 += 32) {
            __syncthreads();
#pragma unroll
            for (int r = 0; r < 3; r++)
                gl_lds16(gb[r] + k0, S + (r * 64 + wave * 16) * 32);
            __syncthreads();
            bf16x8 af[2], bfr[4];
#pragma unroll
            for (int i = 0; i < 2; i++)
                af[i] = *(const bf16x8*)(S + (wm + i * 16 + l15) * 32 + kcol);
#pragma unroll
            for (int j = 0; j < 4; j++)
                bfr[j] = *(const bf16x8*)(S + (128 + j * 16 + l15) * 32 + kcol);
#pragma unroll
            for (int i = 0; i < 2; i++)
#pragma unroll
                for (int j = 0; j < 4; j++)
                    acc[i][j] = __builtin_amdgcn_mfma_f32_16x16x32_bf16(af[i], bfr[j], acc[i][j], 0, 0, 0);
        }
        // V write (bf16): row = m0+wm+i*16+(lane>>4)*4+r, col = n0+j*16+l15
        const int crow = m0 + wm + (lane >> 4) * 4;
#pragma unroll
        for (int i = 0; i < 2; i++)
#pragma unroll
            for (int j = 0; j < 4; j++)
#pragma unroll
                for (int r = 0; r < 4; r++)
                    V[(size_t)(crow + i * 16 + r) * DM + n0 + j * 16 + l15] = f2bf(acc[i][j][r]);
        // csum: this wave's 32 rows = chunk (m0&2047)/32 + wave of (batch, head)
        float s[4];
#pragma unroll
        for (int j = 0; j < 4; j++) {
            s[j] = 0.f;
#pragma unroll
            for (int i = 0; i < 2; i++)
#pragma unroll
                for (int r = 0; r < 4; r++) s[j] += acc[i][j][r];
            s[j] += __shfl_xor(s[j], 16);
            s[j] += __shfl_xor(s[j], 32);
        }
        if (lane < 16) {
            int bi = (m0 >> 11) * NH + head;
            int chunk = ((m0 & (SEQ - 1)) >> 5) + wave;
#pragma unroll
            for (int j = 0; j < 4; j++)
                csum[(bi * NCHUNK + chunk) * 64 + j * 16 + lane] = s[j];
        }
    }
}

// z[q] = a*v[q] + w * sum_{p>q} v[p];  V bf16 in, Zb bf16 out [MROWS,512]
// 256 blocks x 256 threads; each sub-wave handles one chunk (serial len 32)
__global__ __launch_bounds__(256) void zbuild(
    const unsigned short* __restrict__ V, const float* __restrict__ csum,
    const float* __restrict__ cA, const float* __restrict__ cW,
    unsigned short* __restrict__ Zb) {
    int ci = blockIdx.x * 4 + (threadIdx.x >> 6);
    int h = threadIdx.x & 63;
    int c = ci & (NCHUNK - 1), bi = ci >> 6;
    int i = bi & 7, b = bi >> 3;
    float r = 0.f;
    for (int cc = c + 1; cc < NCHUNK; cc++) r += csum[((bi << 6) + cc) * 64 + h];
    for (int j = CHUNK - 1; j >= 0; j--) {
        int p = c * CHUNK + j;
        size_t row = (size_t)(b * SEQ + p);
        float v = bf2f(V[row * DM + i * DH + h]);
        float a = cA[row * NH + i], w = cW[row * NH + i];
        Zb[row * DM + i * DH + h] = f2bf(fmaf(a, v, w * r));
        r += v;
    }
}

// ---- C[M,N] = A[M,K] * B[N,K]^T (bf16 in, fp32 out), templated tiles -------
template<int TM, int TN, int WM, int WN>
__global__ __launch_bounds__(256) void gemm_bt(
    const unsigned short* __restrict__ A, const unsigned short* __restrict__ B,
    float* __restrict__ C, int M, int N, int K)
{
    constexpr int ROWS = TM + TN;
    constexpr int ROUNDS = ROWS / 64;
    constexpr int MI = WM / 16, NJ = WN / 16;
    constexpr int WAVES_N = TN / WN;
    __shared__ __align__(16) unsigned short S[ROWS * 32];
    const int t = threadIdx.x, lane = t & 63, wave = t >> 6;
    const int wm = (wave / WAVES_N) * WM, wn = (wave % WAVES_N) * WN;
    const int m0 = blockIdx.x * TM, n0 = blockIdx.y * TN;
    const int lr = lane >> 2, lc = (lane & 3) * 8;

    const unsigned short* gbase[ROUNDS];
#pragma unroll
    for (int r = 0; r < ROUNDS; r++) {
        int grow = r * 64 + wave * 16 + lr;
        gbase[r] = (grow < TM) ? A + (size_t)(m0 + grow) * K + lc
                               : B + (size_t)(n0 + grow - TM) * K + lc;
    }

    f32x4 acc[MI][NJ];
#pragma unroll
    for (int i = 0; i < MI; i++)
#pragma unroll
        for (int j = 0; j < NJ; j++) { f32x4 z = {0.f,0.f,0.f,0.f}; acc[i][j] = z; }

    const int mrow = wm + (lane & 15);
    const int nrow = TM + wn + (lane & 15);
    const int kcol = (lane >> 4) * 8;

    for (int k0 = 0; k0 < K; k0 += 32) {
        __syncthreads();
#pragma unroll
        for (int r = 0; r < ROUNDS; r++)
            gl_lds16(gbase[r] + k0, S + (r * 64 + wave * 16) * 32);
        __syncthreads();
        bf16x8 af[MI], bfr[NJ];
#pragma unroll
        for (int i = 0; i < MI; i++)
            af[i] = *(const bf16x8*)(S + (mrow + i * 16) * 32 + kcol);
#pragma unroll
        for (int j = 0; j < NJ; j++)
            bfr[j] = *(const bf16x8*)(S + (nrow + j * 16) * 32 + kcol);
#pragma unroll
        for (int i = 0; i < MI; i++)
#pragma unroll
            for (int j = 0; j < NJ; j++)
                acc[i][j] = __builtin_amdgcn_mfma_f32_16x16x32_bf16(af[i], bfr[j], acc[i][j], 0, 0, 0);
    }
    const int crow = m0 + wm + (lane >> 4) * 4;
    const int ccol = n0 + wn + (lane & 15);
#pragma unroll
    for (int i = 0; i < MI; i++)
#pragma unroll
        for (int j = 0; j < NJ; j++)
#pragma unroll
            for (int r = 0; r < 4; r++)
                C[(size_t)(crow + i * 16 + r) * N + ccol + j * 16] = acc[i][j][r];
}

extern "C" void kernel_launch(void* const* d_in, const int* in_sizes, int n_in,
                              void* d_out, int out_size, void* d_ws, size_t ws_size,
                              hipStream_t stream) {
    const float* x  = (const float*)d_in[0];
    const float* Wq = (const float*)d_in[1];
    const float* Wk = (const float*)d_in[2];
    const float* Wv = (const float*)d_in[3];
    const float* Wo = (const float*)d_in[4];
    float* out = (float*)d_out;     // [2,2048,512] fp32
    char* ws = (char*)d_ws;         // ~15 MB used

    unsigned short* xb = (unsigned short*)(ws);             // 4 MB   [4096,512] bf16
    unsigned short* wb = (unsigned short*)(ws + 4194304);   // 2 MB   wqk|wv|wo bf16
    unsigned short* V  = (unsigned short*)(ws + 6291456);   // 4 MB   [4096,512] bf16
    float* cA = (float*)(ws + 10485760);                    // 128 KB [4096,8]
    float* cW = (float*)(ws + 10616832);                    // 128 KB
    float* cs = (float*)(ws + 10747904);                    // 256 KB [16*64,64]
    unsigned short* Zb = (unsigned short*)(ws + 11010048);  // 4 MB   [4096,512] bf16

    cvt_all<<<3072, 256, 0, stream>>>((const float4*)x, (const float4*)Wq,
                                      (const float4*)Wk, (const float4*)Wv,
                                      (const float4*)Wo, (ushort4*)xb, (ushort4*)wb);
    proj<<<512, 256, 0, stream>>>(xb, wb, cA, cW, V, cs);
    zbuild<<<256, 256, 0, stream>>>(V, cs, cA, cW, Zb);
    // out = Z @ Wo^T; 64x64 tile -> 512 blocks (2/CU)
    gemm_bt<64, 64, 32, 32><<<dim3(64, 8, 1), 256, 0, stream>>>(
        Zb, wb + 786432, out, MROWS, DM, DM);
}